// Round 2
// baseline (1170.545 us; speedup 1.0000x reference)
//
#include <hip/hip_runtime.h>
#include <cstdint>
#include <cstddef>

typedef _Float16 f16;
typedef _Float16 f16x8 __attribute__((ext_vector_type(8)));
typedef float f32x4 __attribute__((ext_vector_type(4)));

#define HW    3600
#define HWP   3712   // padded hw: 29*128
#define KTOT  3072   // 2048 + 1024 concatenated channels
#define NB    2
#define FC    256

static __device__ __forceinline__ void load_lds16(const void* g, void* l) {
  __builtin_amdgcn_global_load_lds(
      (const __attribute__((address_space(1))) uint32_t*)g,
      (__attribute__((address_space(3))) uint32_t*)l, 16, 0, 0);
}

// ---------------------------------------------------------------- K1: channel sums of squares per pixel
// grid (58, 4 feats, 2 b), block 256. feat: 0=fq4 1=fs4 2=fq3 3=fs3
__global__ __launch_bounds__(256) void norm_sums_kernel(
    const float* __restrict__ fq4, const float* __restrict__ fs4,
    const float* __restrict__ fq3, const float* __restrict__ fs3,
    float* __restrict__ sums /* [4][NB][HWP] */) {
  int t = threadIdx.x;
  int p0 = blockIdx.x * 64;
  int f = blockIdx.y;
  int b = blockIdx.z;
  const float* src = (f == 0) ? fq4 : (f == 1) ? fs4 : (f == 2) ? fq3 : fs3;
  int C = (f < 2) ? 2048 : 1024;
  int pix = p0 + (t & 63);
  int cp = t >> 6;
  float acc = 0.f;
  if (pix < HW) {
    const float* col = src + (size_t)b * C * HW + pix;
    for (int c = cp; c < C; c += 4) {
      float x = col[(size_t)c * HW];
      acc += x * x;
    }
  }
  __shared__ float part[4][64];
  part[cp][t & 63] = acc;
  __syncthreads();
  if (t < 64) {
    float s = part[0][t] + part[1][t] + part[2][t] + part[3][t];
    sums[((size_t)f * NB + b) * HWP + p0 + t] = s;
  }
}

// ---------------------------------------------------------------- K2: normalize + transpose to [pixel][k] fp16
// grid (48 ktiles, 58 ptiles, 4 = b*2+tensor), block 256
__global__ __launch_bounds__(256) void pack_qs_kernel(
    const float* __restrict__ fq4, const float* __restrict__ fs4,
    const float* __restrict__ fq3, const float* __restrict__ fs3,
    const float* __restrict__ sums, f16* __restrict__ Qp, f16* __restrict__ Sp) {
  int t = threadIdx.x;
  int k0 = blockIdx.x * 64;
  int p0 = blockIdx.y * 64;
  int b = blockIdx.z >> 1;
  int ten = blockIdx.z & 1;  // 0=Q(query) 1=S(support)
  bool is4 = (k0 < 2048);
  const float* src = is4 ? (ten ? fs4 : fq4) : (ten ? fs3 : fq3);
  int fidx = is4 ? ten : 2 + ten;
  int C = is4 ? 2048 : 1024;
  int cbase = is4 ? k0 : (k0 - 2048);
  __shared__ float tile[64][65];
  int pl = t & 63;
  int pix = p0 + pl;
  {
    bool ok = pix < HW;
    const float* sp = src + ((size_t)b * C + cbase) * HW + pix;
    #pragma unroll
    for (int j = 0; j < 16; ++j) {
      int r = (t >> 6) * 16 + j;
      tile[r][pl] = ok ? sp[(size_t)r * HW] : 0.f;
    }
  }
  __syncthreads();
  f16* dst = (ten ? Sp : Qp) + ((size_t)b * HWP + p0) * KTOT + k0;
  #pragma unroll
  for (int j = 0; j < 16; ++j) {
    int qr = (t >> 6) * 16 + j;
    int q = p0 + qr;
    float sc = 0.f;
    if (q < HW) {
      float sm = sums[((size_t)fidx * NB + b) * HWP + q];
      sc = 1.0f / fmaxf(sqrtf(sm), 1e-12f);
    }
    dst[(size_t)qr * KTOT + (t & 63)] = (f16)(tile[t & 63][qr] * sc);
  }
}

// ---------------------------------------------------------------- K2v: V = f_s as fp16, padded [NB][FC][HWP]
__global__ __launch_bounds__(256) void pack_v_kernel(
    const float* __restrict__ f_s, f16* __restrict__ Vp) {
  int t = threadIdx.x;
  int p0 = blockIdx.x * 64;
  int b = blockIdx.y;
  #pragma unroll 4
  for (int j = 0; j < 64; ++j) {
    int idx = t + j * 256;  // 256c * 64s
    int c = idx >> 6;
    int sl = idx & 63;
    int s = p0 + sl;
    Vp[((size_t)b * FC + c) * HWP + s] =
        (s < HW) ? (f16)f_s[((size_t)b * FC + c) * HW + s] : (f16)0.f;
  }
}

// ---------------------------------------------------------------- K3: logits GEMM, 128x128 tile, BK=64, f16 MFMA
// logits[b][q][s] = 10 * sum_k Qp[q][k]*Sp[s][k]   (10 = TEMP * 0.5 scale-mean)
__global__ __launch_bounds__(256) void gemm_logits_kernel(
    const f16* __restrict__ Qp, const f16* __restrict__ Sp,
    float* __restrict__ logits) {
  int t = threadIdx.x;
  int b = blockIdx.z;
  int q0 = blockIdx.y * 128;
  int s0 = blockIdx.x * 128;
  __shared__ f16 As[128 * 64];
  __shared__ f16 Bs[128 * 64];
  const f16* Ag = Qp + ((size_t)b * HWP + q0) * KTOT;
  const f16* Bg = Sp + ((size_t)b * HWP + s0) * KTOT;
  int lane = t & 63;
  int wave = t >> 6;
  int wr = (wave >> 1) * 64;
  int wc = (wave & 1) * 64;
  int lrow = lane & 15;
  int lk = (lane >> 4) * 8;
  f32x4 acc[4][4];
  #pragma unroll
  for (int i = 0; i < 4; ++i)
    #pragma unroll
    for (int n = 0; n < 4; ++n) acc[i][n] = (f32x4){0.f, 0.f, 0.f, 0.f};
  int srow = t >> 3;         // 0..31
  int scol = (t & 7) * 8;    // halves
  for (int kk = 0; kk < KTOT; kk += 64) {
    #pragma unroll
    for (int it = 0; it < 4; ++it) {
      int r = srow + it * 32;
      load_lds16(Ag + (size_t)r * KTOT + kk + scol, (char*)As + (it * 256 + t) * 16);
    }
    #pragma unroll
    for (int it = 0; it < 4; ++it) {
      int r = srow + it * 32;
      load_lds16(Bg + (size_t)r * KTOT + kk + scol, (char*)Bs + (it * 256 + t) * 16);
    }
    __syncthreads();
    #pragma unroll
    for (int kc = 0; kc < 2; ++kc) {
      f16x8 af[4], bf[4];
      #pragma unroll
      for (int i = 0; i < 4; ++i)
        af[i] = *(const f16x8*)&As[(wr + i * 16 + lrow) * 64 + kc * 32 + lk];
      #pragma unroll
      for (int n = 0; n < 4; ++n)
        bf[n] = *(const f16x8*)&Bs[(wc + n * 16 + lrow) * 64 + kc * 32 + lk];
      #pragma unroll
      for (int i = 0; i < 4; ++i)
        #pragma unroll
        for (int n = 0; n < 4; ++n)
          acc[i][n] = __builtin_amdgcn_mfma_f32_16x16x32_f16(af[i], bf[n], acc[i][n], 0, 0, 0);
    }
    __syncthreads();
  }
  float* out = logits + (size_t)b * HWP * HWP;
  #pragma unroll
  for (int i = 0; i < 4; ++i) {
    int qb = q0 + wr + i * 16 + (lane >> 4) * 4;
    #pragma unroll
    for (int n = 0; n < 4; ++n) {
      int s = s0 + wc + n * 16 + lrow;
      #pragma unroll
      for (int r = 0; r < 4; ++r)
        out[(size_t)(qb + r) * HWP + s] = acc[i][n][r] * 10.0f;
    }
  }
}

// ---------------------------------------------------------------- K3b: row max of logits, full-GPU streaming
// grid (464, 2): 8 rows/block x 32 lanes/row
__global__ __launch_bounds__(256) void rowmax_kernel(
    const float* __restrict__ logits, float* __restrict__ mrow /* [NB][HWP] */) {
  int t = threadIdx.x;
  int b = blockIdx.y;
  int row = blockIdx.x * 8 + (t >> 5);
  int ln = t & 31;
  const f32x4* rp = (const f32x4*)(logits + ((size_t)b * HWP + row) * HWP);
  float m = -3.4e38f;
  for (int c = ln; c < 225; c += 32) {  // 225*16 = 3600 valid floats exactly
    f32x4 v = rp[c];
    m = fmaxf(m, fmaxf(fmaxf(v[0], v[1]), fmaxf(v[2], v[3])));
  }
  #pragma unroll
  for (int off = 16; off; off >>= 1) m = fmaxf(m, __shfl_xor(m, off));
  if (ln == 0) mrow[(size_t)b * HWP + row] = m;
}

// ---------------------------------------------------------------- K4: fused softmax + PV
// block: 64 q-rows, 256 threads (4 waves). wave w owns c-rows w*64..w*64+63.
__global__ __launch_bounds__(256) void softmax_pv_kernel(
    const float* __restrict__ logits, const f16* __restrict__ Vp,
    const float* __restrict__ mrow_g, float* __restrict__ att_out) {
  int t = threadIdx.x;
  int b = blockIdx.y;
  int Q0 = blockIdx.x * 64;
  int lane = t & 63;
  int wave = t >> 6;
  __shared__ float linv[64];
  __shared__ f16 Pt[64][72];  // [q][s], stride 72 halves = 144 B
  const float* lg = logits + ((size_t)b * HWP + Q0) * HWP;
  float mr[16];
  #pragma unroll
  for (int j = 0; j < 16; ++j)
    mr[j] = mrow_g[(size_t)b * HWP + Q0 + wave * 16 + j];
  float rs[16];
  #pragma unroll
  for (int j = 0; j < 16; ++j) rs[j] = 0.f;
  f32x4 acc[4][4];
  #pragma unroll
  for (int i = 0; i < 4; ++i)
    #pragma unroll
    for (int n = 0; n < 4; ++n) acc[i][n] = (f32x4){0.f, 0.f, 0.f, 0.f};
  int lrow = lane & 15;
  int lk = (lane >> 4) * 8;
  for (int sb = 0; sb < 57; ++sb) {
    int s0 = sb * 64;
    {  // generate P tile (each wave its 16 q-rows, lane = s); fold row-sum into rs[]
      int sl = t & 63;
      int s = s0 + sl;
      bool ok = s < HW;
      #pragma unroll
      for (int j = 0; j < 16; ++j) {
        int q = wave * 16 + j;
        float p = ok ? __expf(lg[(size_t)q * HWP + s] - mr[j]) : 0.f;
        f16 ph = (f16)p;
        Pt[q][sl] = ph;
        rs[j] += (float)ph;  // denominator matches the fp16 P the MFMA consumes
      }
    }
    __syncthreads();
    #pragma unroll
    for (int kc = 0; kc < 2; ++kc) {
      f16x8 bf[4];
      #pragma unroll
      for (int n = 0; n < 4; ++n)
        bf[n] = *(const f16x8*)&Pt[n * 16 + lrow][kc * 32 + lk];
      #pragma unroll
      for (int i = 0; i < 4; ++i) {
        f16x8 av = *(const f16x8*)(Vp + ((size_t)b * FC + wave * 64 + i * 16 + lrow) * HWP +
                                   s0 + kc * 32 + lk);
        #pragma unroll
        for (int n = 0; n < 4; ++n)
          acc[i][n] = __builtin_amdgcn_mfma_f32_16x16x32_f16(av, bf[n], acc[i][n], 0, 0, 0);
      }
    }
    __syncthreads();
  }
  // 64-lane butterfly per owned q-row -> denominators
  #pragma unroll
  for (int j = 0; j < 16; ++j) {
    float s = rs[j];
    #pragma unroll
    for (int off = 32; off; off >>= 1) s += __shfl_xor(s, off);
    if (lane == 0) linv[wave * 16 + j] = 1.0f / s;
  }
  __syncthreads();
  #pragma unroll
  for (int i = 0; i < 4; ++i) {
    int c = wave * 64 + i * 16 + (lane >> 4) * 4;
    #pragma unroll
    for (int n = 0; n < 4; ++n) {
      int q = Q0 + n * 16 + lrow;
      if (q < HW) {
        float li = linv[n * 16 + lrow];
        #pragma unroll
        for (int r = 0; r < 4; ++r)
          att_out[((size_t)b * FC + c + r) * HW + q] = acc[i][n][r] * li;
      }
    }
  }
}

// ---------------------------------------------------------------- K5a: per-pixel inverse norms of f_q and att_fq
__global__ __launch_bounds__(256) void out_norms_kernel(
    const float* __restrict__ f_q, const float* __restrict__ att,
    float* __restrict__ ninv /* [2][NB][HWP] */) {
  int t = threadIdx.x;
  int p0 = blockIdx.x * 64;
  int b = blockIdx.y;
  int pix = p0 + (t & 63);
  int cp = t >> 6;
  float a1 = 0.f, a2 = 0.f;
  if (pix < HW) {
    const float* c1 = f_q + (size_t)b * FC * HW + pix;
    const float* c2 = att + (size_t)b * FC * HW + pix;
    for (int c = cp; c < FC; c += 4) {
      float x = c1[(size_t)c * HW];
      a1 += x * x;
      float y = c2[(size_t)c * HW];
      a2 += y * y;
    }
  }
  __shared__ float p1[4][64], p2[4][64];
  p1[cp][t & 63] = a1;
  p2[cp][t & 63] = a2;
  __syncthreads();
  if (t < 64) {
    float s1 = p1[0][t] + p1[1][t] + p1[2][t] + p1[3][t];
    float s2 = p2[0][t] + p2[1][t] + p2[2][t] + p2[3][t];
    ninv[(size_t)b * HWP + p0 + t] = 1.0f / fmaxf(sqrtf(s1), 1e-12f);
    ninv[((size_t)NB + b) * HWP + p0 + t] = 1.0f / fmaxf(sqrtf(s2), 1e-12f);
  }
}

// ---------------------------------------------------------------- K5b: fq = l2n(f_q) + 0.5*l2n(att_fq)
__global__ __launch_bounds__(256) void final_combine_kernel(
    const float* __restrict__ f_q, const float* __restrict__ att,
    const float* __restrict__ ninv, float* __restrict__ fq_out) {
  int idx = blockIdx.x * 256 + threadIdx.x;  // < 2*256*3600
  int p = idx % HW;
  int bc = idx / HW;
  int b = bc >> 8;
  float n1 = ninv[(size_t)b * HWP + p];
  float n2 = ninv[((size_t)NB + b) * HWP + p];
  fq_out[idx] = f_q[idx] * n1 + 0.5f * att[idx] * n2;
}

// ----------------------------------------------------------------
extern "C" void kernel_launch(void* const* d_in, const int* in_sizes, int n_in,
                              void* d_out, int out_size, void* d_ws, size_t ws_size,
                              hipStream_t stream) {
  const float* fq3 = (const float*)d_in[0];
  const float* fs3 = (const float*)d_in[1];
  const float* fq4 = (const float*)d_in[2];
  const float* fs4 = (const float*)d_in[3];
  const float* f_q = (const float*)d_in[4];
  const float* f_s = (const float*)d_in[5];
  float* out = (float*)d_out;
  float* att_out = out + (size_t)NB * FC * HW;  // second tuple element

  // workspace layout (bytes)
  constexpr size_t QP_B   = (size_t)NB * HWP * KTOT * 2;       // 45,613,056
  constexpr size_t VP_B   = (size_t)NB * FC * HWP * 2;         //  3,801,088
  constexpr size_t LG_B   = (size_t)NB * HWP * HWP * 4;        // 110,231,552
  constexpr size_t SUMS_B = (size_t)4 * NB * HWP * 4;          //     118,784
  constexpr size_t NINV_B = (size_t)2 * NB * HWP * 4;          //      59,392
  constexpr size_t MROW_B = (size_t)NB * HWP * 4;              //      29,696
  constexpr size_t NEED = QP_B * 2 + VP_B + LG_B + SUMS_B + NINV_B + MROW_B;  // ~196 MiB
  if (ws_size < NEED) return;  // leaves d_out poisoned -> loud failure instead of corruption

  char* ws = (char*)d_ws;
  f16* Qp = (f16*)ws;
  f16* Sp = (f16*)(ws + QP_B);
  f16* Vp = (f16*)(ws + QP_B * 2);
  float* logits = (float*)(ws + QP_B * 2 + VP_B);
  float* sums = (float*)(ws + QP_B * 2 + VP_B + LG_B);
  float* ninv = (float*)(ws + QP_B * 2 + VP_B + LG_B + SUMS_B);
  float* mrow = (float*)(ws + QP_B * 2 + VP_B + LG_B + SUMS_B + NINV_B);

  norm_sums_kernel<<<dim3(58, 4, 2), 256, 0, stream>>>(fq4, fs4, fq3, fs3, sums);
  pack_qs_kernel<<<dim3(48, 58, 4), 256, 0, stream>>>(fq4, fs4, fq3, fs3, sums, Qp, Sp);
  pack_v_kernel<<<dim3(58, 2), 256, 0, stream>>>(f_s, Vp);
  gemm_logits_kernel<<<dim3(29, 29, 2), 256, 0, stream>>>(Qp, Sp, logits);
  rowmax_kernel<<<dim3(464, 2), 256, 0, stream>>>(logits, mrow);
  softmax_pv_kernel<<<dim3(57, 2), 256, 0, stream>>>(logits, Vp, mrow, att_out);
  out_norms_kernel<<<dim3(57, 2), 256, 0, stream>>>(f_q, att_out, ninv);
  final_combine_kernel<<<7200, 256, 0, stream>>>(f_q, att_out, ninv, out);
}

// Round 5
// 925.098 us; speedup vs baseline: 1.2653x; 1.2653x over previous
//
#include <hip/hip_runtime.h>
#include <cstdint>
#include <cstddef>

typedef _Float16 f16;
typedef _Float16 f16x8 __attribute__((ext_vector_type(8)));
typedef float f32x4 __attribute__((ext_vector_type(4)));

#define HW    3600
#define HWP   3712   // padded hw: 29*128
#define KTOT  3072   // 2048 + 1024 concatenated channels
#define NB    2
#define FC    256
#define SPLIT 8      // s-dimension split for PV

static __device__ __forceinline__ void load_lds16(const void* g, void* l) {
  __builtin_amdgcn_global_load_lds(
      (const __attribute__((address_space(1))) uint32_t*)g,
      (__attribute__((address_space(3))) uint32_t*)l, 16, 0, 0);
}

// ---------------------------------------------------------------- K1: channel sums of squares per pixel
__global__ __launch_bounds__(256) void norm_sums_kernel(
    const float* __restrict__ fq4, const float* __restrict__ fs4,
    const float* __restrict__ fq3, const float* __restrict__ fs3,
    float* __restrict__ sums /* [4][NB][HWP] */) {
  int t = threadIdx.x;
  int p0 = blockIdx.x * 64;
  int f = blockIdx.y;
  int b = blockIdx.z;
  const float* src = (f == 0) ? fq4 : (f == 1) ? fs4 : (f == 2) ? fq3 : fs3;
  int C = (f < 2) ? 2048 : 1024;
  int pix = p0 + (t & 63);
  int cp = t >> 6;
  float acc = 0.f;
  if (pix < HW) {
    const float* col = src + (size_t)b * C * HW + pix;
    for (int c = cp; c < C; c += 4) {
      float x = col[(size_t)c * HW];
      acc += x * x;
    }
  }
  __shared__ float part[4][64];
  part[cp][t & 63] = acc;
  __syncthreads();
  if (t < 64) {
    float s = part[0][t] + part[1][t] + part[2][t] + part[3][t];
    sums[((size_t)f * NB + b) * HWP + p0 + t] = s;
  }
}

// ---------------------------------------------------------------- K2: normalize + transpose to [pixel][k] fp16
__global__ __launch_bounds__(256) void pack_qs_kernel(
    const float* __restrict__ fq4, const float* __restrict__ fs4,
    const float* __restrict__ fq3, const float* __restrict__ fs3,
    const float* __restrict__ sums, f16* __restrict__ Qp, f16* __restrict__ Sp) {
  int t = threadIdx.x;
  int k0 = blockIdx.x * 64;
  int p0 = blockIdx.y * 64;
  int b = blockIdx.z >> 1;
  int ten = blockIdx.z & 1;  // 0=Q(query) 1=S(support)
  bool is4 = (k0 < 2048);
  const float* src = is4 ? (ten ? fs4 : fq4) : (ten ? fs3 : fq3);
  int fidx = is4 ? ten : 2 + ten;
  int C = is4 ? 2048 : 1024;
  int cbase = is4 ? k0 : (k0 - 2048);
  __shared__ float tile[64][65];
  int pl = t & 63;
  int pix = p0 + pl;
  {
    bool ok = pix < HW;
    const float* sp = src + ((size_t)b * C + cbase) * HW + pix;
    #pragma unroll
    for (int j = 0; j < 16; ++j) {
      int r = (t >> 6) * 16 + j;
      tile[r][pl] = ok ? sp[(size_t)r * HW] : 0.f;
    }
  }
  __syncthreads();
  f16* dst = (ten ? Sp : Qp) + ((size_t)b * HWP + p0) * KTOT + k0;
  #pragma unroll
  for (int j = 0; j < 16; ++j) {
    int qr = (t >> 6) * 16 + j;
    int q = p0 + qr;
    float sc = 0.f;
    if (q < HW) {
      float sm = sums[((size_t)fidx * NB + b) * HWP + q];
      sc = 1.0f / fmaxf(sqrtf(sm), 1e-12f);
    }
    dst[(size_t)qr * KTOT + (t & 63)] = (f16)(tile[t & 63][qr] * sc);
  }
}

// ---------------------------------------------------------------- K2v: V = f_s as fp16, padded [NB][FC][HWP]
__global__ __launch_bounds__(256) void pack_v_kernel(
    const float* __restrict__ f_s, f16* __restrict__ Vp) {
  int t = threadIdx.x;
  int p0 = blockIdx.x * 64;
  int b = blockIdx.y;
  #pragma unroll 4
  for (int j = 0; j < 64; ++j) {
    int idx = t + j * 256;  // 256c * 64s
    int c = idx >> 6;
    int sl = idx & 63;
    int s = p0 + sl;
    Vp[((size_t)b * FC + c) * HWP + s] =
        (s < HW) ? (f16)f_s[((size_t)b * FC + c) * HW + s] : (f16)0.f;
  }
}

// ---------------------------------------------------------------- K3: logits GEMM, 128x128 tile, BK=64, f16 MFMA
__global__ __launch_bounds__(256) void gemm_logits_kernel(
    const f16* __restrict__ Qp, const f16* __restrict__ Sp,
    float* __restrict__ logits) {
  int t = threadIdx.x;
  int b = blockIdx.z;
  int q0 = blockIdx.y * 128;
  int s0 = blockIdx.x * 128;
  __shared__ f16 As[128 * 64];
  __shared__ f16 Bs[128 * 64];
  const f16* Ag = Qp + ((size_t)b * HWP + q0) * KTOT;
  const f16* Bg = Sp + ((size_t)b * HWP + s0) * KTOT;
  int lane = t & 63;
  int wave = t >> 6;
  int wr = (wave >> 1) * 64;
  int wc = (wave & 1) * 64;
  int lrow = lane & 15;
  int lk = (lane >> 4) * 8;
  f32x4 acc[4][4];
  #pragma unroll
  for (int i = 0; i < 4; ++i)
    #pragma unroll
    for (int n = 0; n < 4; ++n) acc[i][n] = (f32x4){0.f, 0.f, 0.f, 0.f};
  int srow = t >> 3;         // 0..31
  int scol = (t & 7) * 8;    // halves
  for (int kk = 0; kk < KTOT; kk += 64) {
    #pragma unroll
    for (int it = 0; it < 4; ++it) {
      int r = srow + it * 32;
      load_lds16(Ag + (size_t)r * KTOT + kk + scol, (char*)As + (it * 256 + t) * 16);
    }
    #pragma unroll
    for (int it = 0; it < 4; ++it) {
      int r = srow + it * 32;
      load_lds16(Bg + (size_t)r * KTOT + kk + scol, (char*)Bs + (it * 256 + t) * 16);
    }
    __syncthreads();
    #pragma unroll
    for (int kc = 0; kc < 2; ++kc) {
      f16x8 af[4], bf[4];
      #pragma unroll
      for (int i = 0; i < 4; ++i)
        af[i] = *(const f16x8*)&As[(wr + i * 16 + lrow) * 64 + kc * 32 + lk];
      #pragma unroll
      for (int n = 0; n < 4; ++n)
        bf[n] = *(const f16x8*)&Bs[(wc + n * 16 + lrow) * 64 + kc * 32 + lk];
      #pragma unroll
      for (int i = 0; i < 4; ++i)
        #pragma unroll
        for (int n = 0; n < 4; ++n)
          acc[i][n] = __builtin_amdgcn_mfma_f32_16x16x32_f16(af[i], bf[n], acc[i][n], 0, 0, 0);
    }
    __syncthreads();
  }
  float* out = logits + (size_t)b * HWP * HWP;
  #pragma unroll
  for (int i = 0; i < 4; ++i) {
    int qb = q0 + wr + i * 16 + (lane >> 4) * 4;
    #pragma unroll
    for (int n = 0; n < 4; ++n) {
      int s = s0 + wc + n * 16 + lrow;
      #pragma unroll
      for (int r = 0; r < 4; ++r)
        out[(size_t)(qb + r) * HWP + s] = acc[i][n][r] * 10.0f;
    }
  }
}

// ---------------------------------------------------------------- K3b: row max + exp-sum of logits (two-pass)
// grid (464, 2): 8 rows/block x 32 lanes/row. Writes mrow and linv = 1/sum.
// NOTE: a 3600-float row is 900 f32x4 vectors (NOT 225 — that bug shipped in R3:
// both passes covered only cols 0..899, inflating att by ~4x per pixel).
__global__ __launch_bounds__(256) void rowmax_sum_kernel(
    const float* __restrict__ logits, float* __restrict__ mrow,
    float* __restrict__ linv /* [NB][HWP] each */) {
  int t = threadIdx.x;
  int b = blockIdx.y;
  int row = blockIdx.x * 8 + (t >> 5);
  int ln = t & 31;
  const f32x4* rp = (const f32x4*)(logits + ((size_t)b * HWP + row) * HWP);
  float m = -3.4e38f;
  for (int c = ln; c < 900; c += 32) {  // 900*4 = 3600 valid floats exactly
    f32x4 v = rp[c];
    m = fmaxf(m, fmaxf(fmaxf(v[0], v[1]), fmaxf(v[2], v[3])));
  }
  #pragma unroll
  for (int off = 16; off; off >>= 1) m = fmaxf(m, __shfl_xor(m, off));
  // pass 2: exp-sum (row L2-resident after pass 1; exp(x-m) <= 1 by true max)
  float s = 0.f;
  for (int c = ln; c < 900; c += 32) {
    f32x4 v = rp[c];
    s += __expf(v[0] - m) + __expf(v[1] - m) + __expf(v[2] - m) + __expf(v[3] - m);
  }
  #pragma unroll
  for (int off = 16; off; off >>= 1) s += __shfl_xor(s, off);
  if (ln == 0) {
    mrow[(size_t)b * HWP + row] = m;
    linv[(size_t)b * HWP + row] = 1.0f / s;
  }
}

// ---------------------------------------------------------------- K4: PV partial, s-split 8-way
// grid (SPLIT, 57, 2), block 256 (4 waves; wave w owns c-rows w*64..w*64+63)
__global__ __launch_bounds__(256) void pv_part_kernel(
    const float* __restrict__ logits, const f16* __restrict__ Vp,
    const float* __restrict__ mrow_g, float* __restrict__ U_part) {
  int t = threadIdx.x;
  int sp = blockIdx.x;
  int b = blockIdx.z;
  int Q0 = blockIdx.y * 64;
  int lane = t & 63;
  int wave = t >> 6;
  __shared__ f16 Pt[64][72];  // [q][s], stride 72 halves = 144 B
  const float* lg = logits + ((size_t)b * HWP + Q0) * HWP;
  float mr[16];
  #pragma unroll
  for (int j = 0; j < 16; ++j)
    mr[j] = mrow_g[(size_t)b * HWP + Q0 + wave * 16 + j];
  f32x4 acc[4][4];
  #pragma unroll
  for (int i = 0; i < 4; ++i)
    #pragma unroll
    for (int n = 0; n < 4; ++n) acc[i][n] = (f32x4){0.f, 0.f, 0.f, 0.f};
  int lrow = lane & 15;
  int lk = (lane >> 4) * 8;
  for (int sb = sp; sb < 57; sb += SPLIT) {
    int s0 = sb * 64;
    {  // P tile: each wave its 16 q-rows, lane = s
      int sl = t & 63;
      int s = s0 + sl;
      bool ok = s < HW;
      #pragma unroll
      for (int j = 0; j < 16; ++j) {
        int q = wave * 16 + j;
        float p = ok ? __expf(lg[(size_t)q * HWP + s] - mr[j]) : 0.f;
        Pt[q][sl] = (f16)p;
      }
    }
    __syncthreads();
    #pragma unroll
    for (int kc = 0; kc < 2; ++kc) {
      f16x8 bf[4];
      #pragma unroll
      for (int n = 0; n < 4; ++n)
        bf[n] = *(const f16x8*)&Pt[n * 16 + lrow][kc * 32 + lk];
      #pragma unroll
      for (int i = 0; i < 4; ++i) {
        f16x8 av = *(const f16x8*)(Vp + ((size_t)b * FC + wave * 64 + i * 16 + lrow) * HWP +
                                   s0 + kc * 32 + lk);
        #pragma unroll
        for (int n = 0; n < 4; ++n)
          acc[i][n] = __builtin_amdgcn_mfma_f32_16x16x32_f16(av, bf[n], acc[i][n], 0, 0, 0);
      }
    }
    __syncthreads();
  }
  // store partial tile (unnormalized); buffer is HWP-padded so no q guard needed
  float* up = U_part + ((size_t)sp * NB + b) * FC * HWP;
  #pragma unroll
  for (int i = 0; i < 4; ++i) {
    int c = wave * 64 + i * 16 + (lane >> 4) * 4;
    #pragma unroll
    for (int n = 0; n < 4; ++n) {
      int q = Q0 + n * 16 + lrow;
      #pragma unroll
      for (int r = 0; r < 4; ++r)
        up[(size_t)(c + r) * HWP + q] = acc[i][n][r];
    }
  }
}

// ---------------------------------------------------------------- K4b: reduce 8 partials -> U (in place, split 0)
__global__ __launch_bounds__(256) void reduce_u_kernel(float* __restrict__ U_part) {
  const size_t N4 = (size_t)NB * FC * HWP / 4;        // 475,136 f32x4
  const size_t STR4 = (size_t)NB * FC * HWP / 4;      // per-split stride in vec4
  size_t idx = (size_t)blockIdx.x * 256 + threadIdx.x;
  f32x4* p = (f32x4*)U_part;
  for (size_t i = idx; i < N4; i += (size_t)928 * 256) {
    f32x4 v = p[i];
    #pragma unroll
    for (int s = 1; s < SPLIT; ++s) v += p[(size_t)s * STR4 + i];
    p[i] = v;
  }
}

// ---------------------------------------------------------------- K5: normalize + combine
// grid (225, 2), block 256 = 16 px x 16 c-partitions
__global__ __launch_bounds__(256) void final_fused_kernel(
    const float* __restrict__ f_q, const float* __restrict__ U,
    const float* __restrict__ linv, float* __restrict__ fq_out,
    float* __restrict__ att_out) {
  int t = threadIdx.x;
  int b = blockIdx.y;
  int pl = t & 15;
  int cp = t >> 4;
  int pix = blockIdx.x * 16 + pl;  // always < 3600
  float a1 = 0.f, a2 = 0.f;
  const float* fqc = f_q + (size_t)b * FC * HW + pix;
  const float* uc = U + (size_t)b * FC * HWP + pix;
  for (int c = cp; c < FC; c += 16) {
    float f = fqc[(size_t)c * HW];
    a1 += f * f;
    float u = uc[(size_t)c * HWP];
    a2 += u * u;
  }
  __shared__ float p1[16][17], p2[16][17];
  __shared__ float inv1s[16], nus[16];
  p1[cp][pl] = a1;
  p2[cp][pl] = a2;
  __syncthreads();
  if (t < 16) {
    float s1 = 0.f, s2 = 0.f;
    #pragma unroll
    for (int j = 0; j < 16; ++j) {
      s1 += p1[j][t];
      s2 += p2[j][t];
    }
    inv1s[t] = 1.0f / fmaxf(sqrtf(s1), 1e-12f);
    nus[t] = sqrtf(s2);  // ||U[:,pix]||
  }
  __syncthreads();
  float li = linv[(size_t)b * HWP + pix];
  float inv1 = inv1s[pl];
  float inv2 = 1.0f / fmaxf(nus[pl] * li, 1e-12f);  // 1/max(||att||, eps)
  float* ao = att_out + (size_t)b * FC * HW + pix;
  float* fo = fq_out + (size_t)b * FC * HW + pix;
  for (int c = cp; c < FC; c += 16) {
    float u = uc[(size_t)c * HWP];
    float att = u * li;
    ao[(size_t)c * HW] = att;
    float f = fqc[(size_t)c * HW];
    fo[(size_t)c * HW] = f * inv1 + 0.5f * att * inv2;
  }
}

// ----------------------------------------------------------------
extern "C" void kernel_launch(void* const* d_in, const int* in_sizes, int n_in,
                              void* d_out, int out_size, void* d_ws, size_t ws_size,
                              hipStream_t stream) {
  const float* fq3 = (const float*)d_in[0];
  const float* fs3 = (const float*)d_in[1];
  const float* fq4 = (const float*)d_in[2];
  const float* fs4 = (const float*)d_in[3];
  const float* f_q = (const float*)d_in[4];
  const float* f_s = (const float*)d_in[5];
  float* out = (float*)d_out;
  float* att_out = out + (size_t)NB * FC * HW;  // second tuple element

  // workspace layout (bytes)
  constexpr size_t QP_B   = (size_t)NB * HWP * KTOT * 2;       // 45,613,056
  constexpr size_t VP_B   = (size_t)NB * FC * HWP * 2;         //  3,801,088
  constexpr size_t LG_B   = (size_t)NB * HWP * HWP * 4;        // 110,231,552
  constexpr size_t SUMS_B = (size_t)4 * NB * HWP * 4;          //     118,784
  constexpr size_t MROW_B = (size_t)NB * HWP * 4;              //      29,696
  constexpr size_t NEED = QP_B * 2 + VP_B + LG_B + SUMS_B + 2 * MROW_B;  // ~196 MiB
  // U_part (SPLIT * NB*FC*HWP*4 = 60.8 MB) aliases the dead Qp+Sp region (91.2 MB)
  static_assert((size_t)SPLIT * NB * FC * HWP * 4 <= QP_B * 2, "U_part must fit in Qp+Sp");
  if (ws_size < NEED) return;  // loud failure instead of corruption

  char* ws = (char*)d_ws;
  f16* Qp = (f16*)ws;
  f16* Sp = (f16*)(ws + QP_B);
  f16* Vp = (f16*)(ws + QP_B * 2);
  float* logits = (float*)(ws + QP_B * 2 + VP_B);
  float* sums = (float*)(ws + QP_B * 2 + VP_B + LG_B);
  float* mrow = (float*)(ws + QP_B * 2 + VP_B + LG_B + SUMS_B);
  float* linv = (float*)(ws + QP_B * 2 + VP_B + LG_B + SUMS_B + MROW_B);
  float* U_part = (float*)ws;  // alias: valid only after gemm_logits consumed Qp/Sp

  norm_sums_kernel<<<dim3(58, 4, 2), 256, 0, stream>>>(fq4, fs4, fq3, fs3, sums);
  pack_qs_kernel<<<dim3(48, 58, 4), 256, 0, stream>>>(fq4, fs4, fq3, fs3, sums, Qp, Sp);
  pack_v_kernel<<<dim3(58, 2), 256, 0, stream>>>(f_s, Vp);
  gemm_logits_kernel<<<dim3(29, 29, 2), 256, 0, stream>>>(Qp, Sp, logits);
  rowmax_sum_kernel<<<dim3(464, 2), 256, 0, stream>>>(logits, mrow, linv);
  pv_part_kernel<<<dim3(SPLIT, 57, 2), 256, 0, stream>>>(logits, Vp, mrow, U_part);
  reduce_u_kernel<<<928, 256, 0, stream>>>(U_part);
  final_fused_kernel<<<dim3(225, 2), 256, 0, stream>>>(f_q, U_part, linv, out, att_out);
}

// Round 6
// 899.219 us; speedup vs baseline: 1.3017x; 1.0288x over previous
//
#include <hip/hip_runtime.h>
#include <cstdint>
#include <cstddef>

typedef _Float16 f16;
typedef _Float16 f16x8 __attribute__((ext_vector_type(8)));
typedef float f32x4 __attribute__((ext_vector_type(4)));

#define HW    3600
#define HWP   3712   // padded hw: 29*128
#define KTOT  3072   // 2048 + 1024 concatenated channels
#define NB    2
#define FC    256
#define SPLIT 8      // s-dimension split for PV

static __device__ __forceinline__ void load_lds16(const void* g, void* l) {
  __builtin_amdgcn_global_load_lds(
      (const __attribute__((address_space(1))) uint32_t*)g,
      (__attribute__((address_space(3))) uint32_t*)l, 16, 0, 0);
}

// ---------------------------------------------------------------- K1: channel sums of squares per pixel
__global__ __launch_bounds__(256) void norm_sums_kernel(
    const float* __restrict__ fq4, const float* __restrict__ fs4,
    const float* __restrict__ fq3, const float* __restrict__ fs3,
    float* __restrict__ sums /* [4][NB][HWP] */) {
  int t = threadIdx.x;
  int p0 = blockIdx.x * 64;
  int f = blockIdx.y;
  int b = blockIdx.z;
  const float* src = (f == 0) ? fq4 : (f == 1) ? fs4 : (f == 2) ? fq3 : fs3;
  int C = (f < 2) ? 2048 : 1024;
  int pix = p0 + (t & 63);
  int cp = t >> 6;
  float acc = 0.f;
  if (pix < HW) {
    const float* col = src + (size_t)b * C * HW + pix;
    for (int c = cp; c < C; c += 4) {
      float x = col[(size_t)c * HW];
      acc += x * x;
    }
  }
  __shared__ float part[4][64];
  part[cp][t & 63] = acc;
  __syncthreads();
  if (t < 64) {
    float s = part[0][t] + part[1][t] + part[2][t] + part[3][t];
    sums[((size_t)f * NB + b) * HWP + p0 + t] = s;
  }
}

// ---------------------------------------------------------------- K2: normalize + transpose to [pixel][k] fp16
__global__ __launch_bounds__(256) void pack_qs_kernel(
    const float* __restrict__ fq4, const float* __restrict__ fs4,
    const float* __restrict__ fq3, const float* __restrict__ fs3,
    const float* __restrict__ sums, f16* __restrict__ Qp, f16* __restrict__ Sp) {
  int t = threadIdx.x;
  int k0 = blockIdx.x * 64;
  int p0 = blockIdx.y * 64;
  int b = blockIdx.z >> 1;
  int ten = blockIdx.z & 1;  // 0=Q(query) 1=S(support)
  bool is4 = (k0 < 2048);
  const float* src = is4 ? (ten ? fs4 : fq4) : (ten ? fs3 : fq3);
  int fidx = is4 ? ten : 2 + ten;
  int C = is4 ? 2048 : 1024;
  int cbase = is4 ? k0 : (k0 - 2048);
  __shared__ float tile[64][65];
  int pl = t & 63;
  int pix = p0 + pl;
  {
    bool ok = pix < HW;
    const float* sp = src + ((size_t)b * C + cbase) * HW + pix;
    #pragma unroll
    for (int j = 0; j < 16; ++j) {
      int r = (t >> 6) * 16 + j;
      tile[r][pl] = ok ? sp[(size_t)r * HW] : 0.f;
    }
  }
  __syncthreads();
  f16* dst = (ten ? Sp : Qp) + ((size_t)b * HWP + p0) * KTOT + k0;
  #pragma unroll
  for (int j = 0; j < 16; ++j) {
    int qr = (t >> 6) * 16 + j;
    int q = p0 + qr;
    float sc = 0.f;
    if (q < HW) {
      float sm = sums[((size_t)fidx * NB + b) * HWP + q];
      sc = 1.0f / fmaxf(sqrtf(sm), 1e-12f);
    }
    dst[(size_t)qr * KTOT + (t & 63)] = (f16)(tile[t & 63][qr] * sc);
  }
}

// ---------------------------------------------------------------- K2v: V = f_s as fp16, padded [NB][FC][HWP]
__global__ __launch_bounds__(256) void pack_v_kernel(
    const float* __restrict__ f_s, f16* __restrict__ Vp) {
  int t = threadIdx.x;
  int p0 = blockIdx.x * 64;
  int b = blockIdx.y;
  #pragma unroll 4
  for (int j = 0; j < 64; ++j) {
    int idx = t + j * 256;  // 256c * 64s
    int c = idx >> 6;
    int sl = idx & 63;
    int s = p0 + sl;
    Vp[((size_t)b * FC + c) * HWP + s] =
        (s < HW) ? (f16)f_s[((size_t)b * FC + c) * HW + s] : (f16)0.f;
  }
}

// ---------------------------------------------------------------- K3: logits GEMM, 128x128 tile, BK=64, f16 MFMA
// Output stored as f16 (logits ~ +-0.5 with random-normal features; f16 err ~2e-4).
// T1: bijective XCD-chunk swizzle (nwg=1682 = 8q+r, q=210 r=2; m204 formula) so the
// ~210 consecutive linear ids per XCD share A-panels in that XCD's private L2.
__global__ __launch_bounds__(256) void gemm_logits_kernel(
    const f16* __restrict__ Qp, const f16* __restrict__ Sp,
    f16* __restrict__ logits) {
  int t = threadIdx.x;
  int orig = blockIdx.x + 29 * (blockIdx.y + 29 * blockIdx.z);
  const int qq = 1682 >> 3, rr = 1682 & 7;  // 210, 2
  int xcd = orig & 7, lid = orig >> 3;
  int wg = (xcd < rr ? xcd * (qq + 1) : rr * (qq + 1) + (xcd - rr) * qq) + lid;
  int sx = wg % 29;
  int rest = wg / 29;
  int qy = rest % 29;
  int b = rest / 29;
  int q0 = qy * 128;
  int s0 = sx * 128;
  __shared__ f16 As[128 * 64];
  __shared__ f16 Bs[128 * 64];
  const f16* Ag = Qp + ((size_t)b * HWP + q0) * KTOT;
  const f16* Bg = Sp + ((size_t)b * HWP + s0) * KTOT;
  int lane = t & 63;
  int wave = t >> 6;
  int wr = (wave >> 1) * 64;
  int wc = (wave & 1) * 64;
  int lrow = lane & 15;
  int lk = (lane >> 4) * 8;
  f32x4 acc[4][4];
  #pragma unroll
  for (int i = 0; i < 4; ++i)
    #pragma unroll
    for (int n = 0; n < 4; ++n) acc[i][n] = (f32x4){0.f, 0.f, 0.f, 0.f};
  int srow = t >> 3;         // 0..31
  int scol = (t & 7) * 8;    // halves
  for (int kk = 0; kk < KTOT; kk += 64) {
    #pragma unroll
    for (int it = 0; it < 4; ++it) {
      int r = srow + it * 32;
      load_lds16(Ag + (size_t)r * KTOT + kk + scol, (char*)As + (it * 256 + t) * 16);
    }
    #pragma unroll
    for (int it = 0; it < 4; ++it) {
      int r = srow + it * 32;
      load_lds16(Bg + (size_t)r * KTOT + kk + scol, (char*)Bs + (it * 256 + t) * 16);
    }
    __syncthreads();
    #pragma unroll
    for (int kc = 0; kc < 2; ++kc) {
      f16x8 af[4], bf[4];
      #pragma unroll
      for (int i = 0; i < 4; ++i)
        af[i] = *(const f16x8*)&As[(wr + i * 16 + lrow) * 64 + kc * 32 + lk];
      #pragma unroll
      for (int n = 0; n < 4; ++n)
        bf[n] = *(const f16x8*)&Bs[(wc + n * 16 + lrow) * 64 + kc * 32 + lk];
      #pragma unroll
      for (int i = 0; i < 4; ++i)
        #pragma unroll
        for (int n = 0; n < 4; ++n)
          acc[i][n] = __builtin_amdgcn_mfma_f32_16x16x32_f16(af[i], bf[n], acc[i][n], 0, 0, 0);
    }
    __syncthreads();
  }
  f16* out = logits + (size_t)b * HWP * HWP;
  #pragma unroll
  for (int i = 0; i < 4; ++i) {
    int qb = q0 + wr + i * 16 + (lane >> 4) * 4;
    #pragma unroll
    for (int n = 0; n < 4; ++n) {
      int s = s0 + wc + n * 16 + lrow;
      #pragma unroll
      for (int r = 0; r < 4; ++r)
        out[(size_t)(qb + r) * HWP + s] = (f16)(acc[i][n][r] * 10.0f);
    }
  }
}

// ---------------------------------------------------------------- K3b: row max + exp-sum of f16 logits (two-pass)
// grid (464, 2): 8 rows/block x 32 lanes/row. 3600 valid halves = 450 f16x8 exactly.
__global__ __launch_bounds__(256) void rowmax_sum_kernel(
    const f16* __restrict__ logits, float* __restrict__ mrow,
    float* __restrict__ linv /* [NB][HWP] each */) {
  int t = threadIdx.x;
  int b = blockIdx.y;
  int row = blockIdx.x * 8 + (t >> 5);
  int ln = t & 31;
  const f16x8* rp = (const f16x8*)(logits + ((size_t)b * HWP + row) * HWP);
  float m = -3.4e38f;
  for (int c = ln; c < 450; c += 32) {
    f16x8 v = rp[c];
    float m0 = fmaxf(fmaxf((float)v[0], (float)v[1]), fmaxf((float)v[2], (float)v[3]));
    float m1 = fmaxf(fmaxf((float)v[4], (float)v[5]), fmaxf((float)v[6], (float)v[7]));
    m = fmaxf(m, fmaxf(m0, m1));
  }
  #pragma unroll
  for (int off = 16; off; off >>= 1) m = fmaxf(m, __shfl_xor(m, off));
  float s = 0.f;
  for (int c = ln; c < 450; c += 32) {
    f16x8 v = rp[c];
    #pragma unroll
    for (int e = 0; e < 8; ++e) s += __expf((float)v[e] - m);
  }
  #pragma unroll
  for (int off = 16; off; off >>= 1) s += __shfl_xor(s, off);
  if (ln == 0) {
    mrow[(size_t)b * HWP + row] = m;
    linv[(size_t)b * HWP + row] = 1.0f / s;
  }
}

// ---------------------------------------------------------------- K4: PV partial, s-split 8-way (f16 logits in)
// grid (SPLIT, 57, 2), block 256 (4 waves; wave w owns c-rows w*64..w*64+63)
__global__ __launch_bounds__(256) void pv_part_kernel(
    const f16* __restrict__ logits, const f16* __restrict__ Vp,
    const float* __restrict__ mrow_g, float* __restrict__ U_part) {
  int t = threadIdx.x;
  int sp = blockIdx.x;
  int b = blockIdx.z;
  int Q0 = blockIdx.y * 64;
  int lane = t & 63;
  int wave = t >> 6;
  __shared__ f16 Pt[64][72];  // [q][s], stride 72 halves = 144 B
  const f16* lg = logits + ((size_t)b * HWP + Q0) * HWP;
  float mr[16];
  #pragma unroll
  for (int j = 0; j < 16; ++j)
    mr[j] = mrow_g[(size_t)b * HWP + Q0 + wave * 16 + j];
  f32x4 acc[4][4];
  #pragma unroll
  for (int i = 0; i < 4; ++i)
    #pragma unroll
    for (int n = 0; n < 4; ++n) acc[i][n] = (f32x4){0.f, 0.f, 0.f, 0.f};
  int lrow = lane & 15;
  int lk = (lane >> 4) * 8;
  for (int sb = sp; sb < 57; sb += SPLIT) {
    int s0 = sb * 64;
    {  // P tile: each wave its 16 q-rows, lane = s
      int sl = t & 63;
      int s = s0 + sl;
      bool ok = s < HW;
      #pragma unroll
      for (int j = 0; j < 16; ++j) {
        int q = wave * 16 + j;
        float p = ok ? __expf((float)lg[(size_t)q * HWP + s] - mr[j]) : 0.f;
        Pt[q][sl] = (f16)p;
      }
    }
    __syncthreads();
    #pragma unroll
    for (int kc = 0; kc < 2; ++kc) {
      f16x8 bf[4];
      #pragma unroll
      for (int n = 0; n < 4; ++n)
        bf[n] = *(const f16x8*)&Pt[n * 16 + lrow][kc * 32 + lk];
      #pragma unroll
      for (int i = 0; i < 4; ++i) {
        f16x8 av = *(const f16x8*)(Vp + ((size_t)b * FC + wave * 64 + i * 16 + lrow) * HWP +
                                   s0 + kc * 32 + lk);
        #pragma unroll
        for (int n = 0; n < 4; ++n)
          acc[i][n] = __builtin_amdgcn_mfma_f32_16x16x32_f16(av, bf[n], acc[i][n], 0, 0, 0);
      }
    }
    __syncthreads();
  }
  float* up = U_part + ((size_t)sp * NB + b) * FC * HWP;
  #pragma unroll
  for (int i = 0; i < 4; ++i) {
    int c = wave * 64 + i * 16 + (lane >> 4) * 4;
    #pragma unroll
    for (int n = 0; n < 4; ++n) {
      int q = Q0 + n * 16 + lrow;
      #pragma unroll
      for (int r = 0; r < 4; ++r)
        up[(size_t)(c + r) * HWP + q] = acc[i][n][r];
    }
  }
}

// ---------------------------------------------------------------- K5: 8-way U reduce + normalize + combine (fused)
// grid (225, 2), block 256 = 16 px x 16 c-partitions; 16 c-iters fully unrolled
// so uv[] stays in registers (rule: no runtime-indexed reg arrays).
__global__ __launch_bounds__(256) void final_fused_kernel(
    const float* __restrict__ f_q, const float* __restrict__ U_part,
    const float* __restrict__ linv, float* __restrict__ fq_out,
    float* __restrict__ att_out) {
  int t = threadIdx.x;
  int b = blockIdx.y;
  int pl = t & 15;
  int cp = t >> 4;
  int pix = blockIdx.x * 16 + pl;  // always < 3600
  const size_t SSTR = (size_t)NB * FC * HWP;  // per-split stride
  const float* fqc = f_q + (size_t)b * FC * HW + pix;
  const float* uc = U_part + (size_t)b * FC * HWP + pix;
  float uv[16];
  float a1 = 0.f, a2 = 0.f;
  #pragma unroll
  for (int ci = 0; ci < 16; ++ci) {
    int c = cp + ci * 16;
    float u = 0.f;
    #pragma unroll
    for (int s = 0; s < SPLIT; ++s) u += uc[(size_t)s * SSTR + (size_t)c * HWP];
    uv[ci] = u;
    a2 += u * u;
    float f = fqc[(size_t)c * HW];
    a1 += f * f;
  }
  __shared__ float p1[16][17], p2[16][17];
  __shared__ float inv1s[16], nus[16];
  p1[cp][pl] = a1;
  p2[cp][pl] = a2;
  __syncthreads();
  if (t < 16) {
    float s1 = 0.f, s2 = 0.f;
    #pragma unroll
    for (int j = 0; j < 16; ++j) {
      s1 += p1[j][t];
      s2 += p2[j][t];
    }
    inv1s[t] = 1.0f / fmaxf(sqrtf(s1), 1e-12f);
    nus[t] = sqrtf(s2);  // ||U[:,pix]||
  }
  __syncthreads();
  float li = linv[(size_t)b * HWP + pix];
  float inv1 = inv1s[pl];
  float inv2 = 1.0f / fmaxf(nus[pl] * li, 1e-12f);  // 1/max(||att||, eps)
  float* ao = att_out + (size_t)b * FC * HW + pix;
  float* fo = fq_out + (size_t)b * FC * HW + pix;
  #pragma unroll
  for (int ci = 0; ci < 16; ++ci) {
    int c = cp + ci * 16;
    float att = uv[ci] * li;
    ao[(size_t)c * HW] = att;
    float f = fqc[(size_t)c * HW];
    fo[(size_t)c * HW] = f * inv1 + 0.5f * att * inv2;
  }
}

// ----------------------------------------------------------------
extern "C" void kernel_launch(void* const* d_in, const int* in_sizes, int n_in,
                              void* d_out, int out_size, void* d_ws, size_t ws_size,
                              hipStream_t stream) {
  const float* fq3 = (const float*)d_in[0];
  const float* fs3 = (const float*)d_in[1];
  const float* fq4 = (const float*)d_in[2];
  const float* fs4 = (const float*)d_in[3];
  const float* f_q = (const float*)d_in[4];
  const float* f_s = (const float*)d_in[5];
  float* out = (float*)d_out;
  float* att_out = out + (size_t)NB * FC * HW;  // second tuple element

  // workspace layout (bytes)
  constexpr size_t QP_B   = (size_t)NB * HWP * KTOT * 2;       // 45,613,056
  constexpr size_t VP_B   = (size_t)NB * FC * HWP * 2;         //  3,801,088
  constexpr size_t LG_B   = (size_t)NB * HWP * HWP * 2;        //  55,115,776 (f16 now)
  constexpr size_t SUMS_B = (size_t)4 * NB * HWP * 4;          //     118,784
  constexpr size_t MROW_B = (size_t)NB * HWP * 4;              //      29,696
  constexpr size_t NEED = QP_B * 2 + VP_B + LG_B + SUMS_B + 2 * MROW_B;  // ~141 MiB
  // U_part (SPLIT * NB*FC*HWP*4 = 60.8 MB) aliases the dead Qp+Sp region (91.2 MB)
  static_assert((size_t)SPLIT * NB * FC * HWP * 4 <= QP_B * 2, "U_part must fit in Qp+Sp");
  if (ws_size < NEED) return;  // loud failure instead of corruption

  char* ws = (char*)d_ws;
  f16* Qp = (f16*)ws;
  f16* Sp = (f16*)(ws + QP_B);
  f16* Vp = (f16*)(ws + QP_B * 2);
  f16* logits = (f16*)(ws + QP_B * 2 + VP_B);
  float* sums = (float*)(ws + QP_B * 2 + VP_B + LG_B);
  float* mrow = (float*)(ws + QP_B * 2 + VP_B + LG_B + SUMS_B);
  float* linv = (float*)(ws + QP_B * 2 + VP_B + LG_B + SUMS_B + MROW_B);
  float* U_part = (float*)ws;  // alias: valid only after gemm_logits consumed Qp/Sp

  norm_sums_kernel<<<dim3(58, 4, 2), 256, 0, stream>>>(fq4, fs4, fq3, fs3, sums);
  pack_qs_kernel<<<dim3(48, 58, 4), 256, 0, stream>>>(fq4, fs4, fq3, fs3, sums, Qp, Sp);
  pack_v_kernel<<<dim3(58, 2), 256, 0, stream>>>(f_s, Vp);
  gemm_logits_kernel<<<dim3(29, 29, 2), 256, 0, stream>>>(Qp, Sp, logits);
  rowmax_sum_kernel<<<dim3(464, 2), 256, 0, stream>>>(logits, mrow, linv);
  pv_part_kernel<<<dim3(SPLIT, 57, 2), 256, 0, stream>>>(logits, Vp, mrow, U_part);
  final_fused_kernel<<<dim3(225, 2), 256, 0, stream>>>(f_q, U_part, linv, out, att_out);
}

// Round 7
// 797.479 us; speedup vs baseline: 1.4678x; 1.1276x over previous
//
#include <hip/hip_runtime.h>
#include <cstdint>
#include <cstddef>

typedef _Float16 f16;
typedef _Float16 f16x8 __attribute__((ext_vector_type(8)));
typedef float f32x4 __attribute__((ext_vector_type(4)));

#define HW    3600
#define HWP   3840   // padded hw: 15*256 (256-tile gemm)
#define KTOT  3072   // 2048 + 1024 concatenated channels
#define NB    2
#define FC    256
#define SPLIT 8      // s-dimension split for PV
#define BK    64
#define NT    (KTOT / BK)   // 48 K-tiles

static __device__ __forceinline__ void load_lds16(const void* g, void* l) {
  __builtin_amdgcn_global_load_lds(
      (const __attribute__((address_space(1))) uint32_t*)g,
      (__attribute__((address_space(3))) uint32_t*)l, 16, 0, 0);
}

#define BARRIER() do { asm volatile("" ::: "memory"); \
                       __builtin_amdgcn_s_barrier();  \
                       asm volatile("" ::: "memory"); } while (0)

// ---------------------------------------------------------------- K1: channel sums of squares per pixel
__global__ __launch_bounds__(256) void norm_sums_kernel(
    const float* __restrict__ fq4, const float* __restrict__ fs4,
    const float* __restrict__ fq3, const float* __restrict__ fs3,
    float* __restrict__ sums /* [4][NB][HWP] */) {
  int t = threadIdx.x;
  int p0 = blockIdx.x * 64;
  int f = blockIdx.y;
  int b = blockIdx.z;
  const float* src = (f == 0) ? fq4 : (f == 1) ? fs4 : (f == 2) ? fq3 : fs3;
  int C = (f < 2) ? 2048 : 1024;
  int pix = p0 + (t & 63);
  int cp = t >> 6;
  float acc = 0.f;
  if (pix < HW) {
    const float* col = src + (size_t)b * C * HW + pix;
    for (int c = cp; c < C; c += 4) {
      float x = col[(size_t)c * HW];
      acc += x * x;
    }
  }
  __shared__ float part[4][64];
  part[cp][t & 63] = acc;
  __syncthreads();
  if (t < 64) {
    float s = part[0][t] + part[1][t] + part[2][t] + part[3][t];
    sums[((size_t)f * NB + b) * HWP + p0 + t] = s;
  }
}

// ---------------------------------------------------------------- K2: normalize + transpose to [pixel][k] fp16
// grid (48, HWP/64=60, 4)
__global__ __launch_bounds__(256) void pack_qs_kernel(
    const float* __restrict__ fq4, const float* __restrict__ fs4,
    const float* __restrict__ fq3, const float* __restrict__ fs3,
    const float* __restrict__ sums, f16* __restrict__ Qp, f16* __restrict__ Sp) {
  int t = threadIdx.x;
  int k0 = blockIdx.x * 64;
  int p0 = blockIdx.y * 64;
  int b = blockIdx.z >> 1;
  int ten = blockIdx.z & 1;  // 0=Q(query) 1=S(support)
  bool is4 = (k0 < 2048);
  const float* src = is4 ? (ten ? fs4 : fq4) : (ten ? fs3 : fq3);
  int fidx = is4 ? ten : 2 + ten;
  int C = is4 ? 2048 : 1024;
  int cbase = is4 ? k0 : (k0 - 2048);
  __shared__ float tile[64][65];
  int pl = t & 63;
  int pix = p0 + pl;
  {
    bool ok = pix < HW;
    const float* sp = src + ((size_t)b * C + cbase) * HW + pix;
    #pragma unroll
    for (int j = 0; j < 16; ++j) {
      int r = (t >> 6) * 16 + j;
      tile[r][pl] = ok ? sp[(size_t)r * HW] : 0.f;
    }
  }
  __syncthreads();
  f16* dst = (ten ? Sp : Qp) + ((size_t)b * HWP + p0) * KTOT + k0;
  #pragma unroll
  for (int j = 0; j < 16; ++j) {
    int qr = (t >> 6) * 16 + j;
    int q = p0 + qr;
    float sc = 0.f;
    if (q < HW) {
      float sm = sums[((size_t)fidx * NB + b) * HWP + q];
      sc = 1.0f / fmaxf(sqrtf(sm), 1e-12f);
    }
    dst[(size_t)qr * KTOT + (t & 63)] = (f16)(tile[t & 63][qr] * sc);
  }
}

// ---------------------------------------------------------------- K2v: V = f_s as fp16, padded [NB][FC][HWP]
// grid (HWP/64=60, 2)
__global__ __launch_bounds__(256) void pack_v_kernel(
    const float* __restrict__ f_s, f16* __restrict__ Vp) {
  int t = threadIdx.x;
  int p0 = blockIdx.x * 64;
  int b = blockIdx.y;
  #pragma unroll 4
  for (int j = 0; j < 64; ++j) {
    int idx = t + j * 256;  // 256c * 64s
    int c = idx >> 6;
    int sl = idx & 63;
    int s = p0 + sl;
    Vp[((size_t)b * FC + c) * HWP + s] =
        (s < HW) ? (f16)f_s[((size_t)b * FC + c) * HW + s] : (f16)0.f;
  }
}

// ---------------------------------------------------------------- K3: logits GEMM — 256x256 tile, 8 waves,
// counted-vmcnt 4-phase schedule (T2 swizzle + T3/T4 + T5). LDS 128 KB double-buffered.
// Per iter: compute K-tile t from buf c, stage K-tile t+1 into buf 1-c (1 half-tile/phase,
// 2 gload_lds each). vmcnt(2) at p0 only — never drains to 0 mid-loop. Swizzle:
// physical 16B-slot = logical-slot ^ (row&7), applied to BOTH the gload global source
// (inverse = same, XOR involution) and the ds_read address; LDS dest stays linear (rule #21).
__global__ __launch_bounds__(512, 2) void gemm_logits_kernel(
    const f16* __restrict__ Qp, const f16* __restrict__ Sp,
    f16* __restrict__ logits) {
  __shared__ f16 lds[65536];  // 2 bufs x (A 2048 + B 2048 slots) x 16B = 128 KB
  int t = threadIdx.x;
  int lane = t & 63;
  int wave = t >> 6;
  // bijective XCD chunking: nwg=450=8*56+2
  int orig = blockIdx.x;
  const int qq = 450 >> 3, rr = 450 & 7;  // 56, 2
  int xcd = orig & 7, lid = orig >> 3;
  int wg = (xcd < rr ? xcd * (qq + 1) : rr * (qq + 1) + (xcd - rr) * qq) + lid;
  int b = wg / 225;
  int rest = wg % 225;
  int qy = rest / 15, sx = rest % 15;
  const f16* Ag = Qp + ((size_t)b * HWP + qy * 256) * KTOT;
  const f16* Bg = Sp + ((size_t)b * HWP + sx * 256) * KTOT;
  const int WR = (wave >> 2) * 128;  // wave row-half
  const int WC = (wave & 3) * 64;    // wave col-quarter
  const int lrow = lane & 15;
  const int g = lane >> 4;

// stage one half-tile (ph in {0,1}) of tensor at slot-base tb (A=0,B=2048) into buf.
// Physical slot S gets the data for logical slot S^((S>>3)&7) -> pre-swizzled source.
#define STAGE(buf, G, tb, ph, kkh) do {                                        \
    _Pragma("unroll")                                                          \
    for (int j = 0; j < 2; ++j) {                                              \
      int S = (ph) * 1024 + j * 512 + t;                                       \
      int Sl = (S & ~7) | ((S ^ (S >> 3)) & 7);                                \
      int row = S >> 3;                                                        \
      load_lds16((G) + (size_t)row * KTOT + (kkh) + (Sl & 7) * 8,              \
                 (char*)lds + ((size_t)(buf) * 4096 + (tb) + S) * 16);         \
    }                                                                          \
  } while (0)

// swizzled fragment read: row R, k-slice ks; cb = compute-buffer base in halves.
#define RD_A(cb, R, ks) \
  (*(const f16x8*)&lds[(cb) + (size_t)(R) * 64 + (((((ks) << 2) | g)) ^ ((R) & 7)) * 8])
#define RD_B(cb, R, ks) \
  (*(const f16x8*)&lds[(cb) + 16384 + (size_t)(R) * 64 + (((((ks) << 2) | g)) ^ ((R) & 7)) * 8])

  f32x4 acc[8][4];
  #pragma unroll
  for (int i = 0; i < 8; ++i)
    #pragma unroll
    for (int n = 0; n < 4; ++n) acc[i][n] = (f32x4){0.f, 0.f, 0.f, 0.f};

  // prologue: stage tile 0 into buf 0 (8 loads in flight)
  STAGE(0, Ag, 0, 0, 0);
  STAGE(0, Ag, 0, 1, 0);
  STAGE(0, Bg, 2048, 0, 0);
  STAGE(0, Bg, 2048, 1, 0);

  for (int tt = 0; tt < NT; ++tt) {
    int c = tt & 1;
    size_t cb = (size_t)c * 32768;  // halves
    int nbuf = 1 - c;
    int kkh = (tt + 1) * BK;
    bool more = (tt + 1 < NT);
    f16x8 aR[4][2], bR[2][2];
    // ---- phase 0: quad (i 0-3, n 0-1); verify current tile landed (all waves)
    if (more) {
      STAGE(nbuf, Ag, 0, 0, kkh);
      asm volatile("s_waitcnt vmcnt(2)" ::: "memory");
    } else {
      asm volatile("s_waitcnt vmcnt(0)" ::: "memory");
    }
    BARRIER();
    #pragma unroll
    for (int ii = 0; ii < 4; ++ii) {
      int R = WR + ii * 16 + lrow;
      aR[ii][0] = RD_A(cb, R, 0);
      aR[ii][1] = RD_A(cb, R, 1);
    }
    #pragma unroll
    for (int nn = 0; nn < 2; ++nn) {
      int R = WC + nn * 16 + lrow;
      bR[nn][0] = RD_B(cb, R, 0);
      bR[nn][1] = RD_B(cb, R, 1);
    }
    __builtin_amdgcn_s_setprio(1);
    #pragma unroll
    for (int ii = 0; ii < 4; ++ii)
      #pragma unroll
      for (int nn = 0; nn < 2; ++nn)
        #pragma unroll
        for (int ks = 0; ks < 2; ++ks)
          acc[ii][nn] = __builtin_amdgcn_mfma_f32_16x16x32_f16(aR[ii][ks], bR[nn][ks], acc[ii][nn], 0, 0, 0);
    __builtin_amdgcn_s_setprio(0);
    BARRIER();
    // ---- phase 1: quad (i 0-3, n 2-3); reuse aR
    if (more) STAGE(nbuf, Ag, 0, 1, kkh);
    #pragma unroll
    for (int nn = 0; nn < 2; ++nn) {
      int R = WC + (2 + nn) * 16 + lrow;
      bR[nn][0] = RD_B(cb, R, 0);
      bR[nn][1] = RD_B(cb, R, 1);
    }
    __builtin_amdgcn_s_setprio(1);
    #pragma unroll
    for (int ii = 0; ii < 4; ++ii)
      #pragma unroll
      for (int nn = 0; nn < 2; ++nn)
        #pragma unroll
        for (int ks = 0; ks < 2; ++ks)
          acc[ii][2 + nn] = __builtin_amdgcn_mfma_f32_16x16x32_f16(aR[ii][ks], bR[nn][ks], acc[ii][2 + nn], 0, 0, 0);
    __builtin_amdgcn_s_setprio(0);
    BARRIER();
    // ---- phase 2: quad (i 4-7, n 0-1)
    if (more) STAGE(nbuf, Bg, 2048, 0, kkh);
    #pragma unroll
    for (int ii = 0; ii < 4; ++ii) {
      int R = WR + (4 + ii) * 16 + lrow;
      aR[ii][0] = RD_A(cb, R, 0);
      aR[ii][1] = RD_A(cb, R, 1);
    }
    #pragma unroll
    for (int nn = 0; nn < 2; ++nn) {
      int R = WC + nn * 16 + lrow;
      bR[nn][0] = RD_B(cb, R, 0);
      bR[nn][1] = RD_B(cb, R, 1);
    }
    __builtin_amdgcn_s_setprio(1);
    #pragma unroll
    for (int ii = 0; ii < 4; ++ii)
      #pragma unroll
      for (int nn = 0; nn < 2; ++nn)
        #pragma unroll
        for (int ks = 0; ks < 2; ++ks)
          acc[4 + ii][nn] = __builtin_amdgcn_mfma_f32_16x16x32_f16(aR[ii][ks], bR[nn][ks], acc[4 + ii][nn], 0, 0, 0);
    __builtin_amdgcn_s_setprio(0);
    BARRIER();
    // ---- phase 3: quad (i 4-7, n 2-3); reuse aR
    if (more) STAGE(nbuf, Bg, 2048, 1, kkh);
    #pragma unroll
    for (int nn = 0; nn < 2; ++nn) {
      int R = WC + (2 + nn) * 16 + lrow;
      bR[nn][0] = RD_B(cb, R, 0);
      bR[nn][1] = RD_B(cb, R, 1);
    }
    __builtin_amdgcn_s_setprio(1);
    #pragma unroll
    for (int ii = 0; ii < 4; ++ii)
      #pragma unroll
      for (int nn = 0; nn < 2; ++nn)
        #pragma unroll
        for (int ks = 0; ks < 2; ++ks)
          acc[4 + ii][2 + nn] = __builtin_amdgcn_mfma_f32_16x16x32_f16(aR[ii][ks], bR[nn][ks], acc[4 + ii][2 + nn], 0, 0, 0);
    __builtin_amdgcn_s_setprio(0);
    BARRIER();  // also fences buf c reads before next iter's p0 stages into it
  }
  f16* out = logits + (size_t)b * HWP * HWP;
  #pragma unroll
  for (int i = 0; i < 8; ++i) {
    int qb = qy * 256 + WR + i * 16 + g * 4;
    #pragma unroll
    for (int n = 0; n < 4; ++n) {
      int s = sx * 256 + WC + n * 16 + lrow;
      #pragma unroll
      for (int r = 0; r < 4; ++r)
        out[(size_t)(qb + r) * HWP + s] = (f16)(acc[i][n][r] * 10.0f);
    }
  }
#undef STAGE
#undef RD_A
#undef RD_B
}

// ---------------------------------------------------------------- K3b: row max + exp-sum of f16 logits (two-pass)
// grid (HWP/8=480, 2): 8 rows/block x 32 lanes/row. 3600 valid halves = 450 f16x8 exactly.
__global__ __launch_bounds__(256) void rowmax_sum_kernel(
    const f16* __restrict__ logits, float* __restrict__ mrow,
    float* __restrict__ linv /* [NB][HWP] each */) {
  int t = threadIdx.x;
  int b = blockIdx.y;
  int row = blockIdx.x * 8 + (t >> 5);
  int ln = t & 31;
  const f16x8* rp = (const f16x8*)(logits + ((size_t)b * HWP + row) * HWP);
  float m = -3.4e38f;
  for (int c = ln; c < 450; c += 32) {
    f16x8 v = rp[c];
    float m0 = fmaxf(fmaxf((float)v[0], (float)v[1]), fmaxf((float)v[2], (float)v[3]));
    float m1 = fmaxf(fmaxf((float)v[4], (float)v[5]), fmaxf((float)v[6], (float)v[7]));
    m = fmaxf(m, fmaxf(m0, m1));
  }
  #pragma unroll
  for (int off = 16; off; off >>= 1) m = fmaxf(m, __shfl_xor(m, off));
  float s = 0.f;
  for (int c = ln; c < 450; c += 32) {
    f16x8 v = rp[c];
    #pragma unroll
    for (int e = 0; e < 8; ++e) s += __expf((float)v[e] - m);
  }
  #pragma unroll
  for (int off = 16; off; off >>= 1) s += __shfl_xor(s, off);
  if (ln == 0) {
    mrow[(size_t)b * HWP + row] = m;
    linv[(size_t)b * HWP + row] = 1.0f / s;
  }
}

// ---------------------------------------------------------------- K4: PV partial, s-split 8-way (f16 logits in)
// grid (SPLIT, 57, 2), block 256 (4 waves; wave w owns c-rows w*64..w*64+63)
__global__ __launch_bounds__(256) void pv_part_kernel(
    const f16* __restrict__ logits, const f16* __restrict__ Vp,
    const float* __restrict__ mrow_g, float* __restrict__ U_part) {
  int t = threadIdx.x;
  int sp = blockIdx.x;
  int b = blockIdx.z;
  int Q0 = blockIdx.y * 64;
  int lane = t & 63;
  int wave = t >> 6;
  __shared__ f16 Pt[64][72];  // [q][s], stride 72 halves = 144 B
  const f16* lg = logits + ((size_t)b * HWP + Q0) * HWP;
  float mr[16];
  #pragma unroll
  for (int j = 0; j < 16; ++j)
    mr[j] = mrow_g[(size_t)b * HWP + Q0 + wave * 16 + j];
  f32x4 acc[4][4];
  #pragma unroll
  for (int i = 0; i < 4; ++i)
    #pragma unroll
    for (int n = 0; n < 4; ++n) acc[i][n] = (f32x4){0.f, 0.f, 0.f, 0.f};
  int lrow = lane & 15;
  int lk = (lane >> 4) * 8;
  for (int sb = sp; sb < 57; sb += SPLIT) {
    int s0 = sb * 64;
    {  // P tile: each wave its 16 q-rows, lane = s
      int sl = t & 63;
      int s = s0 + sl;
      bool ok = s < HW;
      #pragma unroll
      for (int j = 0; j < 16; ++j) {
        int q = wave * 16 + j;
        float p = ok ? __expf((float)lg[(size_t)q * HWP + s] - mr[j]) : 0.f;
        Pt[q][sl] = (f16)p;
      }
    }
    __syncthreads();
    #pragma unroll
    for (int kc = 0; kc < 2; ++kc) {
      f16x8 bf[4];
      #pragma unroll
      for (int n = 0; n < 4; ++n)
        bf[n] = *(const f16x8*)&Pt[n * 16 + lrow][kc * 32 + lk];
      #pragma unroll
      for (int i = 0; i < 4; ++i) {
        f16x8 av = *(const f16x8*)(Vp + ((size_t)b * FC + wave * 64 + i * 16 + lrow) * HWP +
                                   s0 + kc * 32 + lk);
        #pragma unroll
        for (int n = 0; n < 4; ++n)
          acc[i][n] = __builtin_amdgcn_mfma_f32_16x16x32_f16(av, bf[n], acc[i][n], 0, 0, 0);
      }
    }
    __syncthreads();
  }
  float* up = U_part + ((size_t)sp * NB + b) * FC * HWP;
  #pragma unroll
  for (int i = 0; i < 4; ++i) {
    int c = wave * 64 + i * 16 + (lane >> 4) * 4;
    #pragma unroll
    for (int n = 0; n < 4; ++n) {
      int q = Q0 + n * 16 + lrow;
      #pragma unroll
      for (int r = 0; r < 4; ++r)
        up[(size_t)(c + r) * HWP + q] = acc[i][n][r];
    }
  }
}

// ---------------------------------------------------------------- K5: 8-way U reduce + normalize + combine (fused)
// grid (225, 2), block 256 = 16 px x 16 c-partitions; fully unrolled (regs, no scratch)
__global__ __launch_bounds__(256) void final_fused_kernel(
    const float* __restrict__ f_q, const float* __restrict__ U_part,
    const float* __restrict__ linv, float* __restrict__ fq_out,
    float* __restrict__ att_out) {
  int t = threadIdx.x;
  int b = blockIdx.y;
  int pl = t & 15;
  int cp = t >> 4;
  int pix = blockIdx.x * 16 + pl;  // always < 3600
  const size_t SSTR = (size_t)NB * FC * HWP;  // per-split stride
  const float* fqc = f_q + (size_t)b * FC * HW + pix;
  const float* uc = U_part + (size_t)b * FC * HWP + pix;
  float uv[16];
  float a1 = 0.f, a2 = 0.f;
  #pragma unroll
  for (int ci = 0; ci < 16; ++ci) {
    int c = cp + ci * 16;
    float u = 0.f;
    #pragma unroll
    for (int s = 0; s < SPLIT; ++s) u += uc[(size_t)s * SSTR + (size_t)c * HWP];
    uv[ci] = u;
    a2 += u * u;
    float f = fqc[(size_t)c * HW];
    a1 += f * f;
  }
  __shared__ float p1[16][17], p2[16][17];
  __shared__ float inv1s[16], nus[16];
  p1[cp][pl] = a1;
  p2[cp][pl] = a2;
  __syncthreads();
  if (t < 16) {
    float s1 = 0.f, s2 = 0.f;
    #pragma unroll
    for (int j = 0; j < 16; ++j) {
      s1 += p1[j][t];
      s2 += p2[j][t];
    }
    inv1s[t] = 1.0f / fmaxf(sqrtf(s1), 1e-12f);
    nus[t] = sqrtf(s2);  // ||U[:,pix]||
  }
  __syncthreads();
  float li = linv[(size_t)b * HWP + pix];
  float inv1 = inv1s[pl];
  float inv2 = 1.0f / fmaxf(nus[pl] * li, 1e-12f);  // 1/max(||att||, eps)
  float* ao = att_out + (size_t)b * FC * HW + pix;
  float* fo = fq_out + (size_t)b * FC * HW + pix;
  #pragma unroll
  for (int ci = 0; ci < 16; ++ci) {
    int c = cp + ci * 16;
    float att = uv[ci] * li;
    ao[(size_t)c * HW] = att;
    float f = fqc[(size_t)c * HW];
    fo[(size_t)c * HW] = f * inv1 + 0.5f * att * inv2;
  }
}

// ----------------------------------------------------------------
extern "C" void kernel_launch(void* const* d_in, const int* in_sizes, int n_in,
                              void* d_out, int out_size, void* d_ws, size_t ws_size,
                              hipStream_t stream) {
  const float* fq3 = (const float*)d_in[0];
  const float* fs3 = (const float*)d_in[1];
  const float* fq4 = (const float*)d_in[2];
  const float* fs4 = (const float*)d_in[3];
  const float* f_q = (const float*)d_in[4];
  const float* f_s = (const float*)d_in[5];
  float* out = (float*)d_out;
  float* att_out = out + (size_t)NB * FC * HW;  // second tuple element

  // workspace layout (bytes)
  constexpr size_t QP_B   = (size_t)NB * HWP * KTOT * 2;       // 47,185,920
  constexpr size_t VP_B   = (size_t)NB * FC * HWP * 2;         //  3,932,160
  constexpr size_t LG_B   = (size_t)NB * HWP * HWP * 2;        //  58,982,400 (f16)
  constexpr size_t SUMS_B = (size_t)4 * NB * HWP * 4;          //     122,880
  constexpr size_t MROW_B = (size_t)NB * HWP * 4;              //      30,720
  constexpr size_t NEED = QP_B * 2 + VP_B + LG_B + SUMS_B + 2 * MROW_B;  // ~153 MiB
  // U_part (SPLIT * NB*FC*HWP*4 = 62.9 MB) aliases the dead Qp+Sp region (94.4 MB)
  static_assert((size_t)SPLIT * NB * FC * HWP * 4 <= QP_B * 2, "U_part must fit in Qp+Sp");
  if (ws_size < NEED) return;  // loud failure instead of corruption

  char* ws = (char*)d_ws;
  f16* Qp = (f16*)ws;
  f16* Sp = (f16*)(ws + QP_B);
  f16* Vp = (f16*)(ws + QP_B * 2);
  f16* logits = (f16*)(ws + QP_B * 2 + VP_B);
  float* sums = (float*)(ws + QP_B * 2 + VP_B + LG_B);
  float* mrow = (float*)(ws + QP_B * 2 + VP_B + LG_B + SUMS_B);
  float* linv = (float*)(ws + QP_B * 2 + VP_B + LG_B + SUMS_B + MROW_B);
  float* U_part = (float*)ws;  // alias: valid only after gemm_logits consumed Qp/Sp

  norm_sums_kernel<<<dim3(60, 4, 2), 256, 0, stream>>>(fq4, fs4, fq3, fs3, sums);
  pack_qs_kernel<<<dim3(48, 60, 4), 256, 0, stream>>>(fq4, fs4, fq3, fs3, sums, Qp, Sp);
  pack_v_kernel<<<dim3(60, 2), 256, 0, stream>>>(f_s, Vp);
  gemm_logits_kernel<<<450, 512, 0, stream>>>(Qp, Sp, logits);
  rowmax_sum_kernel<<<dim3(480, 2), 256, 0, stream>>>(logits, mrow, linv);
  pv_part_kernel<<<dim3(SPLIT, 57, 2), 256, 0, stream>>>(logits, Vp, mrow, U_part);
  final_fused_kernel<<<dim3(225, 2), 256, 0, stream>>>(f_q, U_part, linv, out, att_out);
}